// Round 1
// baseline (21460.265 us; speedup 1.0000x reference)
//
#include <hip/hip_runtime.h>

#define BATCH 65536
#define T 500
#define HID 64
#define GHID 52

__device__ __forceinline__ float fast_tanh(float x) {
    // tanh(x) = 1 - 2/(exp(2x)+1); exact saturation at +/-inf
    float e = __expf(2.0f * x);
    return 1.0f - 2.0f / (e + 1.0f);
}

__device__ __forceinline__ float fast_softplus(float x) {
    // softplus(x) = max(x,0) + log(1 + exp(-|x|)) -- overflow-safe
    float e = __expf(-fabsf(x));
    return fmaxf(x, 0.0f) + __logf(1.0f + e);
}

__global__ void __launch_bounds__(256, 1)
node_kernel(const float* __restrict__ y0,
            const float* __restrict__ tt,
            const float* __restrict__ fw1, const float* __restrict__ fb1,
            const float* __restrict__ fw2, const float* __restrict__ fb2,
            const float* __restrict__ fw3, const float* __restrict__ fb3,
            const float* __restrict__ gw1, const float* __restrict__ gb1,
            const float* __restrict__ gw2, const float* __restrict__ gb2,
            const float* __restrict__ gw3, const float* __restrict__ gb3,
            float* __restrict__ out)
{
    const int i = blockIdx.x * blockDim.x + threadIdx.x;
    const float dt = tt[1] - tt[0];

    float ya = y0[2 * i];
    float yb = y0[2 * i + 1];

    // out[0] = y0
    reinterpret_cast<float2*>(out)[i] = make_float2(ya, yb);

    #pragma unroll 1
    for (int s = 1; s < T; ++s) {
        // ---------------- control path u = g(y) ----------------
        float u0, u1;
        {
            float h[GHID];
            #pragma unroll
            for (int j = 0; j < GHID; ++j) {
                float pre = fmaf(gw1[2 * j], ya, fmaf(gw1[2 * j + 1], yb, gb1[j]));
                h[j] = fast_tanh(pre);
            }
            u0 = gb3[0];
            u1 = gb3[1];
            #pragma unroll 1
            for (int j0 = 0; j0 < GHID; j0 += 4) {
                float a0 = gb2[j0 + 0];
                float a1 = gb2[j0 + 1];
                float a2 = gb2[j0 + 2];
                float a3 = gb2[j0 + 3];
                #pragma unroll
                for (int k = 0; k < GHID; ++k) {
                    float hk = h[k];
                    a0 = fmaf(hk, gw2[(j0 + 0) * GHID + k], a0);
                    a1 = fmaf(hk, gw2[(j0 + 1) * GHID + k], a1);
                    a2 = fmaf(hk, gw2[(j0 + 2) * GHID + k], a2);
                    a3 = fmaf(hk, gw2[(j0 + 3) * GHID + k], a3);
                }
                float p0 = fast_softplus(a0);
                float p1 = fast_softplus(a1);
                float p2 = fast_softplus(a2);
                float p3 = fast_softplus(a3);
                u0 = fmaf(gw3[j0 + 0], p0, u0);
                u0 = fmaf(gw3[j0 + 1], p1, u0);
                u0 = fmaf(gw3[j0 + 2], p2, u0);
                u0 = fmaf(gw3[j0 + 3], p3, u0);
                u1 = fmaf(gw3[GHID + j0 + 0], p0, u1);
                u1 = fmaf(gw3[GHID + j0 + 1], p1, u1);
                u1 = fmaf(gw3[GHID + j0 + 2], p2, u1);
                u1 = fmaf(gw3[GHID + j0 + 3], p3, u1);
            }
        }

        // ---------------- drift path f = f(y) ----------------
        float f0, f1;
        {
            float h[HID];
            #pragma unroll
            for (int j = 0; j < HID; ++j) {
                float pre = fmaf(fw1[2 * j], ya, fmaf(fw1[2 * j + 1], yb, fb1[j]));
                h[j] = fast_tanh(pre);
            }
            f0 = fb3[0];
            f1 = fb3[1];
            #pragma unroll 1
            for (int j0 = 0; j0 < HID; j0 += 8) {
                float acc[8];
                #pragma unroll
                for (int jj = 0; jj < 8; ++jj) acc[jj] = fb2[j0 + jj];
                #pragma unroll
                for (int k = 0; k < HID; ++k) {
                    float hk = h[k];
                    #pragma unroll
                    for (int jj = 0; jj < 8; ++jj)
                        acc[jj] = fmaf(hk, fw2[(j0 + jj) * HID + k], acc[jj]);
                }
                #pragma unroll
                for (int jj = 0; jj < 8; ++jj) {
                    float p = fast_softplus(acc[jj]);
                    f0 = fmaf(fw3[j0 + jj], p, f0);
                    f1 = fmaf(fw3[HID + j0 + jj], p, f1);
                }
            }
        }

        ya = fmaf(f0 + u0, dt, ya);
        yb = fmaf(f1 + u1, dt, yb);

        reinterpret_cast<float2*>(out)[(size_t)s * BATCH + i] = make_float2(ya, yb);
    }
}

extern "C" void kernel_launch(void* const* d_in, const int* in_sizes, int n_in,
                              void* d_out, int out_size, void* d_ws, size_t ws_size,
                              hipStream_t stream) {
    const float* y0  = (const float*)d_in[0];
    const float* tt  = (const float*)d_in[1];
    const float* fw1 = (const float*)d_in[2];
    const float* fb1 = (const float*)d_in[3];
    const float* fw2 = (const float*)d_in[4];
    const float* fb2 = (const float*)d_in[5];
    const float* fw3 = (const float*)d_in[6];
    const float* fb3 = (const float*)d_in[7];
    const float* gw1 = (const float*)d_in[8];
    const float* gb1 = (const float*)d_in[9];
    const float* gw2 = (const float*)d_in[10];
    const float* gb2 = (const float*)d_in[11];
    const float* gw3 = (const float*)d_in[12];
    const float* gb3 = (const float*)d_in[13];
    float* out = (float*)d_out;

    dim3 grid(BATCH / 256);
    dim3 block(256);
    hipLaunchKernelGGL(node_kernel, grid, block, 0, stream,
                       y0, tt, fw1, fb1, fw2, fb2, fw3, fb3,
                       gw1, gb1, gw2, gb2, gw3, gb3, out);
}